// Round 5
// baseline (297.032 us; speedup 1.0000x reference)
//
#include <hip/hip_runtime.h>

// OptimizedLinear: out = x@W^T + bias - lr[:,None]*(x@G^T + bias_grad)
// B=4096, IN=OUT=2048, fp32 in/out. bf16 MFMA fused dual-accumulator GEMM.
//
// Round 5: LDS-FREE GEMM. Round-4 post-mortem showed the LDS pipe (24KB write
// + 48KB read per block-K-step) is the binding resource (~36-45us busy/CU vs
// MFMA floor ~31us), phase-serialized by the two __syncthreads. The MFMA
// fragment layout (row=lane&15, k=(lane>>4)*8) is directly loadable from
// row-major-K global memory as 16B/lane dwordx4 (16 x 64B segments/wave), so
// we drop LDS and barriers entirely: 1 wave = 1 block = 128x64 output tile
// (m=8 x n=4 16x16 tiles, dual acc), register double-buffered prefetch.
// Per K32-step: 16 x global_load_dwordx4 (16KB) + 64 MFMA (~1180 cyc/CU) ->
// MFMA-bound; L2 demand ~14 TB/s << 34.5 ceiling.
//
// Lessons carried: hipLaunchCooperativeKernel silently no-ops under this
// harness (R3). SQ_LDS_BANK_CONFLICT==8/global_load_lds_dwordx4 is write-beat
// serialization, not tunable (R1-2). Occupancy is not the lever; LDS traffic
// is (R4). MFMA pipe is per-CU: 16x16x32 ~= 4.6 cyc/CU.

typedef unsigned short ushort_t;
typedef __attribute__((ext_vector_type(8))) short short8;       // 8 bf16 = 4 VGPR
typedef __attribute__((ext_vector_type(8))) unsigned short ushort8;
typedef __attribute__((ext_vector_type(4))) float f32x4;

static constexpr int Kdim = 2048;
static constexpr int Ndim = 2048;

__device__ __forceinline__ unsigned short f2bf(float f) {
    union { float f; unsigned u; } c; c.f = f;
    unsigned u = c.u;
    unsigned r = (u + 0x7fffu + ((u >> 16) & 1u)) >> 16;  // RNE
    return (unsigned short)r;
}

// One launch converts x (uX ushort8-units), W (uW), G (uW). Unit = 8 elems.
__global__ void cvt_all_kernel(const float* __restrict__ x,
                               const float* __restrict__ W,
                               const float* __restrict__ G,
                               ushort_t* __restrict__ xb,
                               ushort_t* __restrict__ wb,
                               ushort_t* __restrict__ gb,
                               int uX, int uW) {
    int u = blockIdx.x * blockDim.x + threadIdx.x;
    const float* src; ushort_t* dst;
    if (u < uX)            { src = x; dst = xb; }
    else if (u < uX + uW)  { src = W; dst = wb; u -= uX; }
    else                   { src = G; dst = gb; u -= uX + uW; }
    int i = u * 8;
    float4 a = *(const float4*)(src + i);
    float4 b = *(const float4*)(src + i + 4);
    ushort8 r;
    r[0] = f2bf(a.x); r[1] = f2bf(a.y); r[2] = f2bf(a.z); r[3] = f2bf(a.w);
    r[4] = f2bf(b.x); r[5] = f2bf(b.y); r[6] = f2bf(b.z); r[7] = f2bf(b.w);
    *(ushort8*)(dst + i) = r;
}

// ---- LDS-free fused dual GEMM ----
// 1 wave per block (64 threads). Wave tile: 128(M) x 64(N) = 8 x 4 MFMA
// tiles, dual accumulators. Grid 32(N) x 32(M) = 1024 waves = 1/SIMD.
__global__ __launch_bounds__(64, 1) void fused_gemm_kernel(
    const ushort_t* __restrict__ xb,   // [4096, 2048] bf16
    const ushort_t* __restrict__ wb,   // [2048, 2048] bf16
    const ushort_t* __restrict__ gb,   // [2048, 2048] bf16
    const float* __restrict__ bias,    // [2048]
    const float* __restrict__ bgrad,   // [2048]
    const float* __restrict__ lr,      // [4096]
    float* __restrict__ out)           // [4096, 2048] fp32
{
    const int lane = threadIdx.x;      // 0..63
    const int fr   = lane & 15;        // fragment row (m or n within 16-tile)
    const int quad = lane >> 4;        // k-granule select (0..3)

    const int bx = blockIdx.x;         // N tile (0..31), 64 wide
    const int by = blockIdx.y;         // M tile (0..31), 128 tall
    const int m0 = by * 128;
    const int n0 = bx * 64;

    // fragment base pointers: lane reads 8 contiguous bf16 at
    // (row, k) = (tile_base + fr, k0 + quad*8)
    const ushort_t* pa = xb + (size_t)(m0 + fr) * Kdim + quad * 8;
    const ushort_t* pw = wb + (size_t)(n0 + fr) * Kdim + quad * 8;
    const ushort_t* pg = gb + (size_t)(n0 + fr) * Kdim + quad * 8;

    f32x4 accB[8][4] = {};   // base = x@W^T
    f32x4 accP[8][4] = {};   // pert = x@G^T

    short8 a0[8], w0[4], g0[4];   // ping
    short8 a1[8], w1[4], g1[4];   // pong

#define LOAD_FRAGS(A, W, G, K)                                             \
    {                                                                      \
        _Pragma("unroll")                                                  \
        for (int mt = 0; mt < 8; ++mt)                                     \
            A[mt] = *(const short8*)(pa + (size_t)mt * 16 * Kdim + (K));   \
        _Pragma("unroll")                                                  \
        for (int nt = 0; nt < 4; ++nt) {                                   \
            W[nt] = *(const short8*)(pw + (size_t)nt * 16 * Kdim + (K));   \
            G[nt] = *(const short8*)(pg + (size_t)nt * 16 * Kdim + (K));   \
        }                                                                  \
    }

#define COMPUTE(A, W, G)                                                   \
    {                                                                      \
        _Pragma("unroll")                                                  \
        for (int mt = 0; mt < 8; ++mt) {                                   \
            _Pragma("unroll")                                              \
            for (int nt = 0; nt < 4; ++nt) {                               \
                accB[mt][nt] = __builtin_amdgcn_mfma_f32_16x16x32_bf16(    \
                    A[mt], W[nt], accB[mt][nt], 0, 0, 0);                  \
                accP[mt][nt] = __builtin_amdgcn_mfma_f32_16x16x32_bf16(    \
                    A[mt], G[nt], accP[mt][nt], 0, 0, 0);                  \
            }                                                              \
        }                                                                  \
    }

    LOAD_FRAGS(a0, w0, g0, 0);

    // K-loop unrolled x2 so the ping/pong buffer index is compile-time.
    for (int k0 = 0; k0 < Kdim; k0 += 64) {
        LOAD_FRAGS(a1, w1, g1, k0 + 32);          // prefetch odd step
        COMPUTE(a0, w0, g0);                      // compute even step
        if (k0 + 64 < Kdim)
            LOAD_FRAGS(a0, w0, g0, k0 + 64);      // prefetch next even step
        COMPUTE(a1, w1, g1);                      // compute odd step
    }

#undef LOAD_FRAGS
#undef COMPUTE

    // epilogue: out = base + bias[n] - lr[m]*(pert + bgrad[n])
    // C/D layout: col = lane&15, row = quad*4 + reg
    const int col = fr;

    float lrv[8][4];
#pragma unroll
    for (int mt = 0; mt < 8; ++mt)
#pragma unroll
        for (int i = 0; i < 4; ++i)
            lrv[mt][i] = lr[m0 + mt * 16 + quad * 4 + i];

#pragma unroll
    for (int nt = 0; nt < 4; ++nt) {
        const int gn = n0 + nt * 16 + col;
        const float bn = bias[gn];
        const float bg = bgrad[gn];
#pragma unroll
        for (int mt = 0; mt < 8; ++mt) {
#pragma unroll
            for (int i = 0; i < 4; ++i) {
                const int gm = m0 + mt * 16 + quad * 4 + i;
                float v = accB[mt][nt][i] + bn - lrv[mt][i] * (accP[mt][nt][i] + bg);
                __builtin_nontemporal_store(v, out + (size_t)gm * Ndim + gn);
            }
        }
    }
}

extern "C" void kernel_launch(void* const* d_in, const int* in_sizes, int n_in,
                              void* d_out, int out_size, void* d_ws, size_t ws_size,
                              hipStream_t stream) {
    const float* x     = (const float*)d_in[0];  // [4096, 2048]
    const float* W     = (const float*)d_in[1];  // [2048, 2048]
    const float* bias  = (const float*)d_in[2];  // [2048]
    const float* G     = (const float*)d_in[3];  // [2048, 2048]
    const float* bgrad = (const float*)d_in[4];  // [2048]
    const float* lr    = (const float*)d_in[5];  // [4096]
    float* out = (float*)d_out;

    const int nX = 4096 * 2048;
    const int nW = 2048 * 2048;

    ushort_t* xb = (ushort_t*)d_ws;
    ushort_t* wb = xb + nX;
    ushort_t* gb = wb + nW;

    const int uX = nX / 8, uW = nW / 8;
    const int totalU = uX + 2 * uW;               // 2,097,152
    cvt_all_kernel<<<totalU / 256, 256, 0, stream>>>(x, W, G, xb, wb, gb, uX, uW);

    dim3 grid(32, 32);   // N tiles x M tiles = 1024 single-wave blocks
    fused_gemm_kernel<<<grid, 64, 0, stream>>>(xb, wb, gb, bias, bgrad, lr, out);
}

// Round 6
// 201.660 us; speedup vs baseline: 1.4729x; 1.4729x over previous
//
#include <hip/hip_runtime.h>

// OptimizedLinear: out = x@W^T + bias - lr[:,None]*(x@G^T + bias_grad)
// B=4096, IN=OUT=2048, fp32 in/out. bf16 MFMA fused dual-accumulator GEMM.
//
// Round 6: restructured K-loop. (1) A-frags read DIRECTLY from global in MFMA
// layout (row-major-K, 16B/lane), register ping-pong — removes A from LDS.
// (2) W/G double-buffered in LDS; staging for step k+1 issued immediately
// AFTER the barrier of step k, so the vmcnt(0) drain at the NEXT barrier
// waits on loads that had a full compute phase (~620 cyc) in flight.
// One barrier per K-step (R1 had 2, with latency fully exposed).
//
// Lessons carried: 128x64/wave tile spills (R5: WRITE_SIZE 611MB — watch
// VGPR_Count/WRITE_SIZE); cooperative launch silently no-ops here (R3);
// SQ_LDS_BANK_CONFLICT = 8/global_load_lds_dwordx4 = write-beat noise (R1-2);
// smaller tiles raise staging traffic per FLOP — wrong direction (R4).
// MFMA floor for this problem: 4.19M x 4.85cyc / 256CU / 2.4GHz = 33 us.

typedef unsigned short ushort_t;
typedef __attribute__((ext_vector_type(8))) short short8;       // 8 bf16 = 4 VGPR
typedef __attribute__((ext_vector_type(8))) unsigned short ushort8;
typedef __attribute__((ext_vector_type(4))) float f32x4;

#define GPTR(p) ((const __attribute__((address_space(1))) void*)(p))
#define LPTR(p) ((__attribute__((address_space(3))) void*)(p))

static constexpr int Kdim = 2048;
static constexpr int Ndim = 2048;

__device__ __forceinline__ unsigned short f2bf(float f) {
    union { float f; unsigned u; } c; c.f = f;
    unsigned u = c.u;
    unsigned r = (u + 0x7fffu + ((u >> 16) & 1u)) >> 16;  // RNE
    return (unsigned short)r;
}

// One launch converts x (uX ushort8-units), W (uW), G (uW). Unit = 8 elems.
__global__ void cvt_all_kernel(const float* __restrict__ x,
                               const float* __restrict__ W,
                               const float* __restrict__ G,
                               ushort_t* __restrict__ xb,
                               ushort_t* __restrict__ wb,
                               ushort_t* __restrict__ gb,
                               int uX, int uW) {
    int u = blockIdx.x * blockDim.x + threadIdx.x;
    const float* src; ushort_t* dst;
    if (u < uX)            { src = x; dst = xb; }
    else if (u < uX + uW)  { src = W; dst = wb; u -= uX; }
    else                   { src = G; dst = gb; u -= uX + uW; }
    int i = u * 8;
    float4 a = *(const float4*)(src + i);
    float4 b = *(const float4*)(src + i + 4);
    ushort8 r;
    r[0] = f2bf(a.x); r[1] = f2bf(a.y); r[2] = f2bf(a.z); r[3] = f2bf(a.w);
    r[4] = f2bf(b.x); r[5] = f2bf(b.y); r[6] = f2bf(b.z); r[7] = f2bf(b.w);
    *(ushort8*)(dst + i) = r;
}

// ---- fused dual GEMM, 128x128 block tile ----
// 256 threads = 4 waves (2x2), each wave 64x64 = 4x4 MFMA tiles, dual acc.
// A: global-direct register ping-pong. W/G: LDS double-buffered.
__global__ __launch_bounds__(256, 2) void fused_gemm_kernel(
    const ushort_t* __restrict__ xb,   // [4096, 2048] bf16
    const ushort_t* __restrict__ wb,   // [2048, 2048] bf16
    const ushort_t* __restrict__ gb,   // [2048, 2048] bf16
    const float* __restrict__ bias,    // [2048]
    const float* __restrict__ bgrad,   // [2048]
    const float* __restrict__ lr,      // [4096]
    float* __restrict__ out)           // [4096, 2048] fp32
{
    __shared__ ushort_t Ws[2][128 * 32];   // 2 x 8 KB
    __shared__ ushort_t Gs[2][128 * 32];   // 2 x 8 KB

    const int t    = threadIdx.x;
    const int wave = t >> 6;
    const int lane = t & 63;
    const int wm   = (wave >> 1) * 64;
    const int wn   = (wave & 1) * 64;
    const int bx   = blockIdx.x;   // N tile (0..15)
    const int by   = blockIdx.y;   // M tile (0..31)

    const int fr   = lane & 15;    // fragment row
    const int quad = lane >> 4;    // k-granule select

    f32x4 accB[4][4] = {};
    f32x4 accP[4][4] = {};

    // --- W/G staging addressing (granule XOR swizzle on the GLOBAL side;
    // LDS dst is HW-forced to wave-uniform base + lane*16) ---
    const int s0 = t,       r0 = s0 >> 2, q0 = (((s0 & 3) ^ (r0 & 3)) * 8);
    const int s1 = 256 + t, r1 = s1 >> 2, q1 = (((s1 & 3) ^ (r1 & 3)) * 8);

    const size_t wBase = (size_t)(bx * 128);
    const ushort_t* gw0 = wb + (wBase + r0) * Kdim + q0;
    const ushort_t* gw1 = wb + (wBase + r1) * Kdim + q1;
    const ushort_t* gg0 = gb + (wBase + r0) * Kdim + q0;
    const ushort_t* gg1 = gb + (wBase + r1) * Kdim + q1;

    const int ldsOff0 = (wave * 64) * 8;
    const int ldsOff1 = (256 + wave * 64) * 8;

    // --- A-frag direct-global addressing (MFMA A layout) ---
    const ushort_t* pa = xb + (size_t)(by * 128 + wm + fr) * Kdim + quad * 8;

    // swizzled k-granule offset for LDS fragment reads
    const int kc = ((quad ^ (fr & 3)) * 8);

#define STAGE(BUF, K)                                                          \
    {                                                                          \
        __builtin_amdgcn_global_load_lds(GPTR(gw0 + (K)), LPTR(Ws[BUF] + ldsOff0), 16, 0, 0); \
        __builtin_amdgcn_global_load_lds(GPTR(gw1 + (K)), LPTR(Ws[BUF] + ldsOff1), 16, 0, 0); \
        __builtin_amdgcn_global_load_lds(GPTR(gg0 + (K)), LPTR(Gs[BUF] + ldsOff0), 16, 0, 0); \
        __builtin_amdgcn_global_load_lds(GPTR(gg1 + (K)), LPTR(Gs[BUF] + ldsOff1), 16, 0, 0); \
    }

#define LOADA(A, K)                                                            \
    {                                                                          \
        _Pragma("unroll")                                                      \
        for (int mt = 0; mt < 4; ++mt)                                         \
            A[mt] = *(const short8*)(pa + (size_t)mt * 16 * Kdim + (K));       \
    }

#define COMPUTE(BUF, A)                                                        \
    {                                                                          \
        short8 wf[4], gf[4];                                                   \
        _Pragma("unroll")                                                      \
        for (int nt = 0; nt < 4; ++nt) {                                       \
            wf[nt] = *(const short8*)(Ws[BUF] + (wn + nt * 16 + fr) * 32 + kc);\
            gf[nt] = *(const short8*)(Gs[BUF] + (wn + nt * 16 + fr) * 32 + kc);\
        }                                                                      \
        _Pragma("unroll")                                                      \
        for (int mt = 0; mt < 4; ++mt) {                                       \
            _Pragma("unroll")                                                  \
            for (int nt = 0; nt < 4; ++nt) {                                   \
                accB[mt][nt] = __builtin_amdgcn_mfma_f32_16x16x32_bf16(        \
                    A[mt], wf[nt], accB[mt][nt], 0, 0, 0);                     \
                accP[mt][nt] = __builtin_amdgcn_mfma_f32_16x16x32_bf16(        \
                    A[mt], gf[nt], accP[mt][nt], 0, 0, 0);                     \
            }                                                                  \
        }                                                                      \
    }

    short8 aCur[4], aNxt[4];
    STAGE(0, 0);
    LOADA(aCur, 0);

    // K-loop unrolled x2 for compile-time ping/pong. One barrier per K32-step;
    // all loads drained by a barrier were issued a full compute-phase earlier.
    for (int k0 = 0; k0 < Kdim; k0 += 64) {
        __syncthreads();                   // drains STAGE(0,k0) / LOADA(aCur,k0)
        STAGE(1, k0 + 32);                 // in flight during even compute
        LOADA(aNxt, k0 + 32);
        COMPUTE(0, aCur);

        __syncthreads();                   // drains STAGE(1) / LOADA(aNxt)
        if (k0 + 64 < Kdim) {
            STAGE(0, k0 + 64);             // in flight during odd compute
            LOADA(aCur, k0 + 64);
        }
        COMPUTE(1, aNxt);
    }

#undef STAGE
#undef LOADA
#undef COMPUTE

    // --- epilogue: out = base + bias[n] - lr[m]*(pert + bgrad[n]) ---
    // C/D layout: col = lane&15, row = quad*4 + reg
    const int col = fr;
    const int gmb = by * 128 + wm;
    const int gnb = bx * 128 + wn;

    float lrv[4][4];
#pragma unroll
    for (int mt = 0; mt < 4; ++mt)
#pragma unroll
        for (int i = 0; i < 4; ++i)
            lrv[mt][i] = lr[gmb + mt * 16 + quad * 4 + i];

#pragma unroll
    for (int nt = 0; nt < 4; ++nt) {
        const int gn = gnb + nt * 16 + col;
        const float bn = bias[gn];
        const float bg = bgrad[gn];
#pragma unroll
        for (int mt = 0; mt < 4; ++mt) {
#pragma unroll
            for (int i = 0; i < 4; ++i) {
                const int gm = gmb + mt * 16 + quad * 4 + i;
                float v = accB[mt][nt][i] + bn - lrv[mt][i] * (accP[mt][nt][i] + bg);
                __builtin_nontemporal_store(v, out + (size_t)gm * Ndim + gn);
            }
        }
    }
}

extern "C" void kernel_launch(void* const* d_in, const int* in_sizes, int n_in,
                              void* d_out, int out_size, void* d_ws, size_t ws_size,
                              hipStream_t stream) {
    const float* x     = (const float*)d_in[0];  // [4096, 2048]
    const float* W     = (const float*)d_in[1];  // [2048, 2048]
    const float* bias  = (const float*)d_in[2];  // [2048]
    const float* G     = (const float*)d_in[3];  // [2048, 2048]
    const float* bgrad = (const float*)d_in[4];  // [2048]
    const float* lr    = (const float*)d_in[5];  // [4096]
    float* out = (float*)d_out;

    const int nX = 4096 * 2048;
    const int nW = 2048 * 2048;

    ushort_t* xb = (ushort_t*)d_ws;
    ushort_t* wb = xb + nX;
    ushort_t* gb = wb + nW;

    const int uX = nX / 8, uW = nW / 8;
    const int totalU = uX + 2 * uW;               // 2,097,152
    cvt_all_kernel<<<totalU / 256, 256, 0, stream>>>(x, W, G, xb, wb, gb, uX, uW);

    dim3 grid(16, 32);   // N tiles x M tiles = 512 blocks = 2/CU
    fused_gemm_kernel<<<grid, 256, 0, stream>>>(xb, wb, gb, bias, bgrad, lr, out);
}

// Round 7
// 165.515 us; speedup vs baseline: 1.7946x; 1.2184x over previous
//
#include <hip/hip_runtime.h>

// OptimizedLinear: out = x@W^T + bias - lr[:,None]*(x@G^T + bias_grad)
// B=4096, IN=OUT=2048, fp32 in/out. bf16 MFMA fused dual-accumulator GEMM.
//
// Round 7: R2 structure with BK=64 (was 32). Ranking across R2/R4/R6 tracks
// MFMA-per-barrier (128 -> 83us, 64 -> 101us, bad-A -> 107us), so double it:
// 256 MFMA per barrier-pair, 32 K-steps. LDS 48KB/block; occupancy is
// grid-limited (512 blocks = 2/CU) so the extra LDS costs nothing (m132's
// BK-raise regression was an occupancy loss we cannot suffer here).
//
// Lessons carried: SQ_LDS_BANK_CONFLICT = 32 x staging-instruction-count
// exactly (R2/R4/R6) — artifact, ignore. Per-wave scattered A-loads poison
// the barrier drain (R6). 256-reg acc tiles spill (R5: WRITE_SIZE 611MB;
// tripwire = WRITE_SIZE >> 40MB). Cooperative launch no-ops here (R3).
// Occupancy is not the lever (R4). MFMA floor ~33us; harness residual ~90us.

typedef unsigned short ushort_t;
typedef __attribute__((ext_vector_type(8))) short short8;       // 8 bf16 = 4 VGPR
typedef __attribute__((ext_vector_type(8))) unsigned short ushort8;
typedef __attribute__((ext_vector_type(4))) float f32x4;

#define GPTR(p) ((const __attribute__((address_space(1))) void*)(p))
#define LPTR(p) ((__attribute__((address_space(3))) void*)(p))

static constexpr int Kdim = 2048;
static constexpr int Ndim = 2048;
static constexpr int BK   = 64;

__device__ __forceinline__ unsigned short f2bf(float f) {
    union { float f; unsigned u; } c; c.f = f;
    unsigned u = c.u;
    unsigned r = (u + 0x7fffu + ((u >> 16) & 1u)) >> 16;  // RNE
    return (unsigned short)r;
}

// One launch converts x (uX ushort8-units), W (uW), G (uW). Unit = 8 elems.
__global__ void cvt_all_kernel(const float* __restrict__ x,
                               const float* __restrict__ W,
                               const float* __restrict__ G,
                               ushort_t* __restrict__ xb,
                               ushort_t* __restrict__ wb,
                               ushort_t* __restrict__ gb,
                               int uX, int uW) {
    int u = blockIdx.x * blockDim.x + threadIdx.x;
    const float* src; ushort_t* dst;
    if (u < uX)            { src = x; dst = xb; }
    else if (u < uX + uW)  { src = W; dst = wb; u -= uX; }
    else                   { src = G; dst = gb; u -= uX + uW; }
    int i = u * 8;
    float4 a = *(const float4*)(src + i);
    float4 b = *(const float4*)(src + i + 4);
    ushort8 r;
    r[0] = f2bf(a.x); r[1] = f2bf(a.y); r[2] = f2bf(a.z); r[3] = f2bf(a.w);
    r[4] = f2bf(b.x); r[5] = f2bf(b.y); r[6] = f2bf(b.z); r[7] = f2bf(b.w);
    *(ushort8*)(dst + i) = r;
}

// ---- fused dual GEMM, 128x128 block tile, BK=64 ----
// 256 threads = 4 waves (2x2), each wave 64x64 = 4x4 MFMA tiles, dual acc.
// LDS tile: 128 rows x 64 k (128B/row), 1024 granules of 16B.
// Granule (row r, g=k/8) lives at slot r*8 + (g ^ (r&7)); swizzle applied on
// the GLOBAL fetch address (LDS dst is HW-forced to base + lane*16).
// Fragment read: addr = row*64 + ((j*4+quad) ^ (row&7))*8 -> bank-group
// histogram is exactly 8 lanes/group for every (j,quad): conflict-free.
__global__ __launch_bounds__(256, 2) void fused_gemm_kernel(
    const ushort_t* __restrict__ xb,   // [4096, 2048] bf16
    const ushort_t* __restrict__ wb,   // [2048, 2048] bf16
    const ushort_t* __restrict__ gb,   // [2048, 2048] bf16
    const float* __restrict__ bias,    // [2048]
    const float* __restrict__ bgrad,   // [2048]
    const float* __restrict__ lr,      // [4096]
    float* __restrict__ out)           // [4096, 2048] fp32
{
    __shared__ ushort_t As[128 * BK];  // 16 KB
    __shared__ ushort_t Ws[128 * BK];  // 16 KB
    __shared__ ushort_t Gs[128 * BK];  // 16 KB

    const int t    = threadIdx.x;
    const int wave = t >> 6;
    const int lane = t & 63;
    const int wm   = (wave >> 1) * 64;
    const int wn   = (wave & 1) * 64;
    const int bx   = blockIdx.x;   // N tile (0..15)
    const int by   = blockIdx.y;   // M tile (0..31)

    const int fr   = lane & 15;    // fragment row
    const int quad = lane >> 4;    // k-granule select (0..3)

    f32x4 accB[4][4] = {};
    f32x4 accP[4][4] = {};

    // --- staging addressing: 4 issues x 256 threads cover 1024 slots ---
    // slot s: row = s>>3, fetched granule q' = (s&7) ^ (row&7)
    int rowI[4], kkI[4];
#pragma unroll
    for (int i = 0; i < 4; ++i) {
        int s = i * 256 + t;
        rowI[i] = s >> 3;
        kkI[i]  = (((s & 7) ^ (rowI[i] & 7)) * 8);
    }

    const size_t aBase = (size_t)(by * 128);
    const size_t wBase = (size_t)(bx * 128);

    const ushort_t* gA[4]; const ushort_t* gW[4]; const ushort_t* gG[4];
    ushort_t* lA[4]; ushort_t* lW[4]; ushort_t* lG[4];
#pragma unroll
    for (int i = 0; i < 4; ++i) {
        gA[i] = xb + (aBase + rowI[i]) * Kdim + kkI[i];
        gW[i] = wb + (wBase + rowI[i]) * Kdim + kkI[i];
        gG[i] = gb + (wBase + rowI[i]) * Kdim + kkI[i];
        const int dst = (i * 256 + wave * 64) * 8;   // wave-uniform + lane*16B
        lA[i] = As + dst; lW[i] = Ws + dst; lG[i] = Gs + dst;
    }

    for (int k0 = 0; k0 < Kdim; k0 += BK) {
#pragma unroll
        for (int i = 0; i < 4; ++i) {
            __builtin_amdgcn_global_load_lds(GPTR(gA[i] + k0), LPTR(lA[i]), 16, 0, 0);
            __builtin_amdgcn_global_load_lds(GPTR(gW[i] + k0), LPTR(lW[i]), 16, 0, 0);
            __builtin_amdgcn_global_load_lds(GPTR(gG[i] + k0), LPTR(lG[i]), 16, 0, 0);
        }
        __syncthreads();

#pragma unroll
        for (int j = 0; j < 2; ++j) {
            const int kc = (((j * 4 + quad) ^ (fr & 7)) * 8);
            short8 af[4], wf[4], gf[4];
#pragma unroll
            for (int mt = 0; mt < 4; ++mt)
                af[mt] = *(const short8*)(As + (wm + mt * 16 + fr) * BK + kc);
#pragma unroll
            for (int nt = 0; nt < 4; ++nt) {
                wf[nt] = *(const short8*)(Ws + (wn + nt * 16 + fr) * BK + kc);
                gf[nt] = *(const short8*)(Gs + (wn + nt * 16 + fr) * BK + kc);
            }
#pragma unroll
            for (int mt = 0; mt < 4; ++mt)
#pragma unroll
                for (int nt = 0; nt < 4; ++nt) {
                    accB[mt][nt] = __builtin_amdgcn_mfma_f32_16x16x32_bf16(
                        af[mt], wf[nt], accB[mt][nt], 0, 0, 0);
                    accP[mt][nt] = __builtin_amdgcn_mfma_f32_16x16x32_bf16(
                        af[mt], gf[nt], accP[mt][nt], 0, 0, 0);
                }
        }
        __syncthreads();
    }

    // --- epilogue: out = base + bias[n] - lr[m]*(pert + bgrad[n]) ---
    // C/D layout: col = lane&15, row = quad*4 + reg
    const int col = fr;
    const int gmb = by * 128 + wm;
    const int gnb = bx * 128 + wn;

    float lrv[4][4];
#pragma unroll
    for (int mt = 0; mt < 4; ++mt)
#pragma unroll
        for (int i = 0; i < 4; ++i)
            lrv[mt][i] = lr[gmb + mt * 16 + quad * 4 + i];

#pragma unroll
    for (int nt = 0; nt < 4; ++nt) {
        const int gn = gnb + nt * 16 + col;
        const float bn = bias[gn];
        const float bg = bgrad[gn];
#pragma unroll
        for (int mt = 0; mt < 4; ++mt) {
#pragma unroll
            for (int i = 0; i < 4; ++i) {
                const int gm = gmb + mt * 16 + quad * 4 + i;
                float v = accB[mt][nt][i] + bn - lrv[mt][i] * (accP[mt][nt][i] + bg);
                __builtin_nontemporal_store(v, out + (size_t)gm * Ndim + gn);
            }
        }
    }
}

extern "C" void kernel_launch(void* const* d_in, const int* in_sizes, int n_in,
                              void* d_out, int out_size, void* d_ws, size_t ws_size,
                              hipStream_t stream) {
    const float* x     = (const float*)d_in[0];  // [4096, 2048]
    const float* W     = (const float*)d_in[1];  // [2048, 2048]
    const float* bias  = (const float*)d_in[2];  // [2048]
    const float* G     = (const float*)d_in[3];  // [2048, 2048]
    const float* bgrad = (const float*)d_in[4];  // [2048]
    const float* lr    = (const float*)d_in[5];  // [4096]
    float* out = (float*)d_out;

    const int nX = 4096 * 2048;
    const int nW = 2048 * 2048;

    ushort_t* xb = (ushort_t*)d_ws;
    ushort_t* wb = xb + nX;
    ushort_t* gb = wb + nW;

    const int uX = nX / 8, uW = nW / 8;
    const int totalU = uX + 2 * uW;               // 2,097,152
    cvt_all_kernel<<<totalU / 256, 256, 0, stream>>>(x, W, G, xb, wb, gb, uX, uW);

    dim3 grid(16, 32);   // N tiles x M tiles = 512 blocks = 2/CU
    fused_gemm_kernel<<<grid, 256, 0, stream>>>(xb, wb, gb, bias, bgrad, lr, out);
}